// Round 3
// baseline (338.582 us; speedup 1.0000x reference)
//
#include <hip/hip_runtime.h>

// Retrace loss: per-row backward recurrence in t-space:
//   Q_ret[T-1] = tQ[T-1]
//   Q_ret[t]   = A[t]*Q_ret[t+1] + B[t],  t = T-2 .. 0
//   A[t] = G*c[t+1],  B[t] = 100*r[t] + G*(eQ[t+1] - c[t+1]*tQ[t+1])
//   c[u] = exp(min(tpp[u]-bpp[u], 0))
// Suffix scan of affine maps (shfl_down), BLOCK=1024 x EPT=4 per row.
//
// R3 change: persistent blocks + REGISTER DOUBLE-BUFFERED row pipeline.
// R0-R2 all landed at ~128us (3.2 TB/s logical, ~50% of achievable) across
// three different shapes/patterns -> pattern & occupancy exonerated. Common
// cause: bulk-synchronous per-row structure (load burst -> barrier'd scan ->
// retire) gives the memory system a ~50% duty cycle, and the allocator
// (VGPR=20!) serialized each row's loads into dependent batches. Now: 256
// blocks (1/CU), 16 rows each; each iteration issues row j+1's 6 float4
// loads into the alternate register buffer (pinned above the compute with
// sched_barrier), then runs row j's scan. Next-row loads are live across the
// scan -> allocator must keep them in flight -> memory streams during the
// barrier/scan phase. Target: ~64-80us (403MB at ~5-6.3TB/s w/ L3 help).

#define NROWS 4096
#define TLEN  4096
#define BLOCK 1024
#define EPT   4
#define NWV   (BLOCK / 64)
#define GRID  256
#define RPB   (NROWS / GRID)   // 16 rows per persistent block

struct RowBuf {
    float4 T, P, Qt, E, Rw, Qm;
    float bt, bp, bq, be;      // lane-63 boundary scalars (guarded use)
};

__device__ __forceinline__ void issue_row(
    RowBuf& b,
    const float* __restrict__ Q,  const float* __restrict__ eQ,
    const float* __restrict__ tQ, const float* __restrict__ rw,
    const float* __restrict__ tpp, const float* __restrict__ bpp,
    long long base, int ua, bool bnd)
{
    b.T  = *(const float4*)(tpp + base + ua);
    b.P  = *(const float4*)(bpp + base + ua);
    b.Qt = *(const float4*)(tQ  + base + ua);
    b.E  = *(const float4*)(eQ  + base + ua);
    b.Rw = *(const float4*)(rw  + base + ua);
    b.Qm = *(const float4*)(Q   + base + ua);
    if (bnd) {   // lane 63 needs thread tid+1's element 0 (L1/L2 hit)
        b.bt = tpp[base + ua + EPT];
        b.bp = bpp[base + ua + EPT];
        b.bq = tQ [base + ua + EPT];
        b.be = eQ [base + ua + EPT];
    }
}

__device__ __forceinline__ void compute_row(
    const RowBuf& b, int row, double* __restrict__ partials,
    float* sWA, float* sWB, float* sRed,
    int tid, int lane, int wv, bool bnd)
{
    constexpr float G = 0.99f;

    const float tv[4] = {b.T.x,  b.T.y,  b.T.z,  b.T.w};
    const float pv[4] = {b.P.x,  b.P.y,  b.P.z,  b.P.w};
    const float qv[4] = {b.Qt.x, b.Qt.y, b.Qt.z, b.Qt.w};
    const float ev[4] = {b.E.x,  b.E.y,  b.E.z,  b.E.w};
    const float rv[4] = {b.Rw.x, b.Rw.y, b.Rw.z, b.Rw.w};
    const float qm[4] = {b.Qm.x, b.Qm.y, b.Qm.z, b.Qm.w};

    // ---- Build the 4 affine maps, k = t - 4*tid ----
    float Aa[4], Bb[4];
    #pragma unroll
    for (int k = 0; k < 3; ++k) {
        const float c  = __expf(fminf(tv[k+1] - pv[k+1], 0.0f));
        const float gc = G * c;
        const float f  = fmaf(-gc, qv[k+1], G * ev[k+1]);
        Aa[k] = gc;
        Bb[k] = fmaf(100.0f, rv[k], f);
    }
    // k = 3: t+1 lives in thread tid+1's element 0.
    {
        float t4 = __shfl_down(tv[0], 1, 64);
        float p4 = __shfl_down(pv[0], 1, 64);
        float q4 = __shfl_down(qv[0], 1, 64);
        float e4 = __shfl_down(ev[0], 1, 64);
        if (bnd) { t4 = b.bt; p4 = b.bp; q4 = b.bq; e4 = b.be; }
        if (tid == BLOCK - 1) {
            // t = T-1: Q_ret = tQ[T-1] exactly (A = 0 kills incoming state).
            Aa[3] = 0.0f;
            Bb[3] = qv[3];
        } else {
            const float c  = __expf(fminf(t4 - p4, 0.0f));
            const float gc = G * c;
            const float f  = fmaf(-gc, q4, G * e4);
            Aa[3] = gc;
            Bb[3] = fmaf(100.0f, rv[3], f);
        }
    }

    // ---- Local composite: f_{4t} o f_{4t+1} o f_{4t+2} o f_{4t+3} ----
    float Ac = 1.0f, Bc = 0.0f;
    #pragma unroll
    for (int k = 3; k >= 0; --k) {
        Bc = fmaf(Aa[k], Bc, Bb[k]);
        Ac = Aa[k] * Ac;
    }

    // ---- Wave-level inclusive SUFFIX scan ----
    float Ai = Ac, Bi = Bc;
    #pragma unroll
    for (int off = 1; off < 64; off <<= 1) {
        const float Ap = __shfl_down(Ai, off, 64);
        const float Bp = __shfl_down(Bi, off, 64);
        if (lane < 64 - off) {
            Bi = fmaf(Ai, Bp, Bi);
            Ai = Ai * Ap;
        }
    }

    // ---- Cross-wave combine ----
    if (lane == 0) { sWA[wv] = Ai; sWB[wv] = Bi; }
    __syncthreads();
    float Bp = 0.0f;
    #pragma unroll
    for (int j = NWV - 1; j >= 1; --j)
        if (j > wv) Bp = fmaf(sWA[j], Bp, sWB[j]);

    float Ae = __shfl_down(Ai, 1, 64);
    float Be = __shfl_down(Bi, 1, 64);
    if (lane == 63) { Ae = 1.0f; Be = 0.0f; }
    float y = fmaf(Ae, Bp, Be);        // Q_ret[4*tid + 4] entering this thread

    // ---- Apply maps + accumulate squared error vs Q ----
    float acc = 0.0f;
    #pragma unroll
    for (int k = 3; k >= 0; --k) {
        y = fmaf(Aa[k], y, Bb[k]);
        const float d = qm[k] - y;
        acc = fmaf(d, d, acc);
    }

    // ---- Block reduction ----
    #pragma unroll
    for (int off = 32; off > 0; off >>= 1)
        acc += __shfl_down(acc, off, 64);
    if (lane == 0) sRed[wv] = acc;
    __syncthreads();
    if (tid == 0) {
        float s = 0.0f;
        #pragma unroll
        for (int j = 0; j < NWV; ++j) s += sRed[j];
        partials[row] = (double)s;     // every row slot written -> poison-safe
    }
    // NOTE cross-row LDS hazards: sWA/sWB reads happen before the 2nd barrier;
    // sRed read (tid 0) happens before tid 0 reaches the NEXT row's 1st
    // barrier, which all other waves wait on before rewriting sRed. Safe.
}

__global__ __launch_bounds__(BLOCK) void retrace_main(
    const float* __restrict__ Q,
    const float* __restrict__ eQ,
    const float* __restrict__ tQ,
    const float* __restrict__ rw,
    const float* __restrict__ tpp,
    const float* __restrict__ bpp,
    double* __restrict__ partials)
{
    __shared__ float sWA[NWV], sWB[NWV], sRed[NWV];

    const int tid  = threadIdx.x;
    const int lane = tid & 63;
    const int wv   = tid >> 6;
    const int ua   = EPT * tid;                    // ascending contiguous float4
    const bool bnd = (lane == 63) && (tid != BLOCK - 1);

    RowBuf bufA, bufB;

    // Prologue: load row for j=0.
    issue_row(bufA, Q, eQ, tQ, rw, tpp, bpp,
              (long long)blockIdx.x * TLEN, ua, bnd);

    #pragma unroll
    for (int j = 0; j < RPB; ++j) {
        const int row = blockIdx.x + j * GRID;
        // Issue next row's loads into the ALTERNATE buffer first (stays in
        // flight across this row's scan), then pin issue order.
        if (j + 1 < RPB) {
            const long long basen = (long long)(blockIdx.x + (j + 1) * GRID) * TLEN;
            if ((j & 1) == 0) issue_row(bufB, Q, eQ, tQ, rw, tpp, bpp, basen, ua, bnd);
            else              issue_row(bufA, Q, eQ, tQ, rw, tpp, bpp, basen, ua, bnd);
        }
        __builtin_amdgcn_sched_barrier(0);   // don't sink prefetch below compute
        if ((j & 1) == 0) compute_row(bufA, row, partials, sWA, sWB, sRed, tid, lane, wv, bnd);
        else              compute_row(bufB, row, partials, sWA, sWB, sRed, tid, lane, wv, bnd);
    }
}

#define FBLOCK 1024

__global__ __launch_bounds__(FBLOCK) void retrace_finalize(
    const double* __restrict__ partials, float* __restrict__ out)
{
    __shared__ double sRed[FBLOCK / 64];
    double s = 0.0;
    #pragma unroll
    for (int i = 0; i < NROWS / FBLOCK; ++i)
        s += partials[threadIdx.x + i * FBLOCK];
    #pragma unroll
    for (int off = 32; off > 0; off >>= 1)
        s += __shfl_down(s, off, 64);
    if ((threadIdx.x & 63) == 0) sRed[threadIdx.x >> 6] = s;
    __syncthreads();
    if (threadIdx.x == 0) {
        double tot = 0.0;
        #pragma unroll
        for (int j = 0; j < FBLOCK / 64; ++j) tot += sRed[j];
        out[0] = (float)(tot / ((double)NROWS * (double)TLEN));
    }
}

extern "C" void kernel_launch(void* const* d_in, const int* in_sizes, int n_in,
                              void* d_out, int out_size, void* d_ws, size_t ws_size,
                              hipStream_t stream)
{
    // setup_inputs order: Q, expected_target_Q, target_Q, rewards,
    //                     target_policy_probs, behaviour_policy_probs
    const float* Q   = (const float*)d_in[0];
    const float* eQ  = (const float*)d_in[1];
    const float* tQ  = (const float*)d_in[2];
    const float* rw  = (const float*)d_in[3];
    const float* tpp = (const float*)d_in[4];
    const float* bpp = (const float*)d_in[5];
    double* partials = (double*)d_ws;       // 4096 doubles = 32 KB scratch

    retrace_main<<<GRID, BLOCK, 0, stream>>>(Q, eQ, tQ, rw, tpp, bpp, partials);
    retrace_finalize<<<1, FBLOCK, 0, stream>>>(partials, (float*)d_out);
}